// Round 18
// baseline (189.712 us; speedup 1.0000x reference)
//
#include <hip/hip_runtime.h>

// Problem: B=2, S=2048, D=1280, H=20, HD=64.  M = B*S = 4096.
#define Sc 2048
#define Dc 1280
#define Hc 20

typedef __bf16 bf16x8 __attribute__((ext_vector_type(8)));
typedef float f32x4 __attribute__((ext_vector_type(4)));
typedef float f32x16 __attribute__((ext_vector_type(16)));
typedef unsigned u32x2 __attribute__((ext_vector_type(2)));

__device__ __forceinline__ __bf16 tobf(float f) {
  union { float f; unsigned u; } a; a.f = f;
  unsigned r = (a.u + 0x7FFFu + ((a.u >> 16) & 1u)) >> 16;  // RNE
  union { unsigned short s; __bf16 b; } o; o.s = (unsigned short)r;
  return o.b;
}

__device__ __forceinline__ void gload16(const __bf16* g, __bf16* l) {
  __builtin_amdgcn_global_load_lds(
      (const __attribute__((address_space(1))) void*)(g),
      (__attribute__((address_space(3))) void*)(l), 16, 0, 0);
}

__device__ __forceinline__ unsigned cvtpk(float lo, float hi) {
  unsigned r;
  asm("v_cvt_pk_bf16_f32 %0, %1, %2" : "=v"(r) : "v"(lo), "v"(hi));
  return r;
}

__device__ __forceinline__ float fexp2(float x) {
#if __has_builtin(__builtin_amdgcn_exp2f)
  return __builtin_amdgcn_exp2f(x);
#else
  return exp2f(x);
#endif
}

__device__ __forceinline__ void plswap(unsigned &a, unsigned &b) {
#if __has_builtin(__builtin_amdgcn_permlane32_swap)
  u32x2 r = __builtin_amdgcn_permlane32_swap(a, b, false, false);
  a = r[0]; b = r[1];
#else
  asm volatile("v_permlane32_swap_b32 %0, %1" : "+v"(a), "+v"(b));
#endif
}

// ---------------- merged prep: cvtx (10240 blk) | wt (1600 blk) | rope (256) --
__global__ __launch_bounds__(256) void k_prep(
    const float* __restrict__ Xq, const float* __restrict__ Xkv,
    __bf16* __restrict__ Xqb, __bf16* __restrict__ Xkvb,
    const float* __restrict__ Wq, const float* __restrict__ Wk,
    const float* __restrict__ Wv, const float* __restrict__ Wo,
    __bf16* __restrict__ Wt,
    float* __restrict__ cosT, float* __restrict__ sinT)
{
  __shared__ __bf16 Ls[64][80];
  const int bid = blockIdx.x;
  const int t = threadIdx.x;
  if (bid < 10240) {
    // ---- X f32 -> bf16 ----
    const int half = bid >= 5120;
    const int i = (bid - (half ? 5120 : 0)) * 256 + t;
    const float* X = half ? Xkv : Xq;
    __bf16* O = half ? Xkvb : Xqb;
    float4 f = ((const float4*)X)[i];
    union { __bf16 b[4]; uint2 u; } pk;
    pk.b[0] = tobf(f.x); pk.b[1] = tobf(f.y); pk.b[2] = tobf(f.z); pk.b[3] = tobf(f.w);
    ((uint2*)O)[i] = pk.u;
  } else if (bid < 11840) {
    // ---- W [k][n] f32 -> Wt [z][n][k] bf16 ----
    int r = bid - 10240;
    const int z = r / 400; r %= 400;
    const int n0 = (r % 20) * 64, k0 = (r / 20) * 64;
    const float* W = (z == 0) ? Wq : (z == 1) ? Wk : (z == 2) ? Wv : Wo;
    __bf16* O = Wt + (size_t)z * Dc * Dc;
    #pragma unroll
    for (int i = 0; i < 4; ++i) {
      int c = t + 256 * i;
      int rr = c >> 4, cc = (c & 15) * 4;
      float4 f = *(const float4*)(W + (size_t)(k0 + rr) * Dc + n0 + cc);
      Ls[cc + 0][rr] = tobf(f.x);
      Ls[cc + 1][rr] = tobf(f.y);
      Ls[cc + 2][rr] = tobf(f.z);
      Ls[cc + 3][rr] = tobf(f.w);
    }
    __syncthreads();
    #pragma unroll
    for (int i = 0; i < 2; ++i) {
      int c = t + 256 * i;
      int rr = c >> 3, cc = (c & 7) * 8;
      *(bf16x8*)(O + (size_t)(n0 + rr) * Dc + k0 + cc) = *(const bf16x8*)(&Ls[rr][cc]);
    }
  } else {
    // ---- RoPE cos/sin table ----
    int i = (bid - 11840) * 256 + t;
    int s = i >> 5, f = i & 31;
    float inv = expf(-(float)f * (logf(10000.0f) / 32.0f));
    float th = (float)s * inv;
    cosT[i] = cosf(th);
    sinT[i] = sinf(th);
  }
}

// ---------------- QKV projection + bias + RoPE; V written pre-transposed ----
// (round-10/12 exact) z=0: q (RoPE, 0.125*log2e), z=1: k (RoPE), z=2: v -> Vt.
__global__ __launch_bounds__(256) void k_proj_qkv(
    const __bf16* __restrict__ Xqb, const __bf16* __restrict__ Xkvb,
    const __bf16* __restrict__ Wt,
    const float* __restrict__ Bq, const float* __restrict__ Bk, const float* __restrict__ Bv,
    const float* __restrict__ cosT, const float* __restrict__ sinT,
    __bf16* __restrict__ Qo, __bf16* __restrict__ Ko, __bf16* __restrict__ Vt)
{
  const int z = blockIdx.z;
  const __bf16* A  = (z == 0) ? Xqb : Xkvb;
  const __bf16* Bm = Wt + (size_t)z * Dc * Dc;
  const float* Bi  = (z == 0) ? Bq : (z == 1) ? Bk : Bv;

  const int m0 = blockIdx.y * 128, n0 = blockIdx.x * 128;
  const int t = threadIdx.x, lane = t & 63, wv = t >> 6;
  const int wr = wv >> 1, wc = wv & 1;
  const int l15 = lane & 15, l4 = lane >> 4;

  __shared__ __bf16 SM[2 * 128 * 64];   // As | Bs ; reused as transpose buf
  __bf16* As = SM;
  __bf16* Bs = SM + 128 * 64;

  const int lrow = lane >> 3;
  const int lcol = ((lane & 7) ^ lrow) * 8;

  f32x4 acc[4][4];
  #pragma unroll
  for (int i = 0; i < 4; ++i)
    #pragma unroll
    for (int j = 0; j < 4; ++j)
      #pragma unroll
      for (int e = 0; e < 4; ++e) acc[i][j][e] = 0.0f;

  for (int kt = 0; kt < 20; ++kt) {
    const int k0 = kt * 64;
    #pragma unroll
    for (int s = 0; s < 4; ++s) {
      int row = wv * 32 + s * 8 + lrow;
      gload16(A  + (size_t)(m0 + row) * Dc + k0 + lcol, As + (wv * 32 + s * 8) * 64);
      gload16(Bm + (size_t)(n0 + row) * Dc + k0 + lcol, Bs + (wv * 32 + s * 8) * 64);
    }
    __syncthreads();

    bf16x8 af[2][4], bfr[2][4];
    #pragma unroll
    for (int kc = 0; kc < 2; ++kc)
      #pragma unroll
      for (int rs = 0; rs < 4; ++rs) {
        int rowa = wr * 64 + rs * 16 + l15;
        int cha  = (kc * 4 + l4) ^ (rowa & 7);
        af[kc][rs] = *(const bf16x8*)(As + rowa * 64 + cha * 8);
        int rowb = wc * 64 + rs * 16 + l15;
        int chb  = (kc * 4 + l4) ^ (rowb & 7);
        bfr[kc][rs] = *(const bf16x8*)(Bs + rowb * 64 + chb * 8);
      }
    #pragma unroll
    for (int kc = 0; kc < 2; ++kc)
      #pragma unroll
      for (int rs = 0; rs < 4; ++rs)
        #pragma unroll
        for (int cb = 0; cb < 4; ++cb)
          acc[rs][cb] = __builtin_amdgcn_mfma_f32_16x16x32_bf16(af[kc][rs], bfr[kc][cb], acc[rs][cb], 0, 0, 0);
    __syncthreads();
  }

  const int head = n0 / 64 + wc;
  if (z < 2) {
    __bf16* O = (z == 0) ? Qo : Ko;
    const float scale = (z == 0) ? 0.125f * 1.4426950408889634f : 1.0f;
    #pragma unroll
    for (int rs = 0; rs < 4; ++rs)
      #pragma unroll
      for (int r = 0; r < 4; ++r) {
        int row = m0 + wr * 64 + rs * 16 + l4 * 4 + r;
        int s = row & (Sc - 1);
        #pragma unroll
        for (int cb = 0; cb < 2; ++cb) {
          int hd = cb * 16 + l15;
          float c  = cosT[s * 32 + hd];
          float sn = sinT[s * 32 + hd];
          float xlo = acc[rs][cb][r]     + Bi[head * 64 + hd];
          float xhi = acc[rs][cb + 2][r] + Bi[head * 64 + hd + 32];
          O[(size_t)row * Dc + head * 64 + hd]      = tobf((xlo * c - xhi * sn) * scale);
          O[(size_t)row * Dc + head * 64 + hd + 32] = tobf((xhi * c + xlo * sn) * scale);
        }
      }
  } else {
    // V: transpose in LDS (swizzled), write Vt[b][h][hd][s] coalesced.
    #pragma unroll
    for (int rs = 0; rs < 4; ++rs)
      #pragma unroll
      for (int r = 0; r < 4; ++r) {
        int row128 = wr * 64 + rs * 16 + l4 * 4 + r;
        #pragma unroll
        for (int cb = 0; cb < 4; ++cb) {
          int hd = cb * 16 + l15;
          float v = acc[rs][cb][r] + Bi[n0 + wc * 64 + hd];
          SM[wc * 8192 + hd * 128 + (row128 ^ ((hd & 7) << 3))] = tobf(v);
        }
      }
    __syncthreads();
    const int bq_ = m0 >> 11, s0 = m0 & (Sc - 1);
    #pragma unroll
    for (int i = 0; i < 8; ++i) {
      int idx = t + 256 * i;        // 2048 chunks of 8
      int hd2 = idx >> 4, sc = idx & 15;
      int hh = hd2 >> 6, hd = hd2 & 63;
      int head2 = n0 / 64 + hh;
      bf16x8 vv = *(const bf16x8*)(&SM[hh * 8192 + hd * 128 + ((sc ^ (hd & 7)) << 3)]);
      *(bf16x8*)(Vt + ((size_t)((bq_ * Hc + head2) * 64 + hd)) * Sc + s0 + sc * 8) = vv;
    }
  }
}

// ---------------- Flash attention: T15 cross-tile pipeline (round-16 exact) -
__global__ __launch_bounds__(256) void k_attn(
    const __bf16* __restrict__ Qb, const __bf16* __restrict__ Kb,
    const __bf16* __restrict__ Vt,
    __bf16* __restrict__ Omb0, __bf16* __restrict__ Omb1, float* __restrict__ ml)
{
  const int f = blockIdx.x;            // 0..1279
  const int xcd = f & 7, ii = f >> 3;  // 0..159
  const int grp = xcd * 5 + (ii >> 5); // 0..39 = b*20+h
  const int rem = ii & 31;
  const int part = rem >> 4;           // 0..1
  const int qt   = rem & 15;           // 0..15
  const int h = grp % Hc, b = grp / Hc;
  const int kvbase = part * 1024;

  const int t = threadIdx.x, lane = t & 63, wv = t >> 6;   // wv 0..3
  const int l31 = lane & 31, hi = lane >> 5;

  __shared__ __bf16 Ks[3][64 * 64];
  __shared__ __bf16 Vs[3][64 * 64];

  const int q0 = qt * 128 + wv * 32;
  const size_t qrow = (size_t)(b * Sc + q0 + l31);

  bf16x8 qreg[4];
  #pragma unroll
  for (int kc = 0; kc < 4; ++kc)
    qreg[kc] = *(const bf16x8*)(Qb + qrow * Dc + h * 64 + kc * 16 + hi * 8);

  f32x16 zc;
  #pragma unroll
  for (int e = 0; e < 16; ++e) zc[e] = 0.0f;

  f32x16 oacc[2];
  oacc[0] = zc; oacc[1] = zc;
  float lrun = 0.0f;

  const int lrow = lane >> 3;
  const int lchunk = ((lane & 7) ^ lrow) * 8;
  const __bf16* Ksrc = Kb + (size_t)b * Sc * Dc + h * 64;
  const __bf16* Vsrc = Vt + (size_t)(b * Hc + h) * 64 * Sc;

  auto STAGE = [&](int t_) {
    int bb = t_ % 3;
    int kv0 = kvbase + t_ * 64;
    #pragma unroll
    for (int i = 0; i < 2; ++i) {
      int rowb = i * 32 + wv * 8;
      gload16(Ksrc + (size_t)(kv0 + rowb + lrow) * Dc + lchunk, &Ks[bb][rowb * 64]);
      gload16(Vsrc + (size_t)(rowb + lrow) * Sc + kv0 + lchunk, &Vs[bb][rowb * 64]);
    }
  };

  auto QK = [&](f32x16 (&s)[2], int t_) {
    const __bf16* Kbuf = &Ks[t_ % 3][0];
    __builtin_amdgcn_s_setprio(1);
    #pragma unroll
    for (int sub = 0; sub < 2; ++sub) {
      int row = sub * 32 + l31;
      {
        int ch = hi ^ (row & 7);
        bf16x8 kf = *(const bf16x8*)(Kbuf + row * 64 + ch * 8);
        s[sub] = __builtin_amdgcn_mfma_f32_32x32x16_bf16(kf, qreg[0], zc, 0, 0, 0);
      }
      #pragma unroll
      for (int kc = 1; kc < 4; ++kc) {
        int ch = (kc * 2 + hi) ^ (row & 7);
        bf16x8 kf = *(const bf16x8*)(Kbuf + row * 64 + ch * 8);
        s[sub] = __builtin_amdgcn_mfma_f32_32x32x16_bf16(kf, qreg[kc], s[sub], 0, 0, 0);
      }
    }
    __builtin_amdgcn_s_setprio(0);
  };

  // fused softmax + PV, per c16 group: exp2 x8 -> lsum -> pack -> 2 PV MFMAs
  auto SMPV = [&](const f32x16 (&s)[2], int t_) {
    const __bf16* Vbuf = &Vs[t_ % 3][0];
    const float* sp = (const float*)&s;
    #pragma unroll
    for (int c16 = 0; c16 < 4; ++c16) {
      float p0 = fexp2(sp[c16 * 8 + 0]), p1 = fexp2(sp[c16 * 8 + 1]);
      float p2 = fexp2(sp[c16 * 8 + 2]), p3 = fexp2(sp[c16 * 8 + 3]);
      float p4 = fexp2(sp[c16 * 8 + 4]), p5 = fexp2(sp[c16 * 8 + 5]);
      float p6 = fexp2(sp[c16 * 8 + 6]), p7 = fexp2(sp[c16 * 8 + 7]);
      lrun += ((p0 + p1) + (p2 + p3)) + ((p4 + p5) + (p6 + p7));
      unsigned w0 = cvtpk(p0, p1);
      unsigned w1 = cvtpk(p2, p3);
      unsigned w2 = cvtpk(p4, p5);
      unsigned w3 = cvtpk(p6, p7);
      plswap(w0, w2);
      plswap(w1, w3);
      union { unsigned w[4]; bf16x8 v; } pa;
      pa.w[0] = w0; pa.w[1] = w1; pa.w[2] = w2; pa.w[3] = w3;
      __builtin_amdgcn_s_setprio(1);
      #pragma unroll
      for (int hb = 0; hb < 2; ++hb) {
        int row = hb * 32 + l31;
        int ch = (c16 * 2 + hi) ^ (row & 7);
        bf16x8 vf = *(const bf16x8*)(Vbuf + row * 64 + ch * 8);
        oacc[hb] = __builtin_amdgcn_mfma_f32_32x32x16_bf16(vf, pa.v, oacc[hb], 0, 0, 0);
      }
      __builtin_amdgcn_s_setprio(0);
    }
  };

  f32x16 sA[2], sB[2];

  // prologue: tiles 0,1 staged and fully landed; QK(0)
  STAGE(0);
  STAGE(1);
  asm volatile("s_waitcnt vmcnt(0)\ns_barrier" ::: "memory");
  QK(sA, 0);

#define ATTN_ITER(T, SCUR, SNXT)                                          \
  {                                                                       \
    if ((T) <= 13) STAGE((T) + 2);                                        \
    if ((T) <= 14) QK(SNXT, (T) + 1);                                     \
    SMPV(SCUR, (T));                                                      \
    if ((T) <= 14) {                                                      \
      asm volatile("s_waitcnt vmcnt(0)\ns_barrier" ::: "memory");         \
    }                                                                     \
  }

  for (int tt = 0; tt < 8; ++tt) {
    ATTN_ITER(2 * tt, sA, sB);
    ATTN_ITER(2 * tt + 1, sB, sA);
  }
#undef ATTN_ITER

  // epilogue: cross-half l; bf16 unnormalized partial O^T -> Omb[part] + l
  lrun += __shfl_xor(lrun, 32);
  __bf16* Ob = part ? Omb1 : Omb0;
  const size_t ridx = (size_t)grp * Sc + q0 + l31;   // row within part
  #pragma unroll
  for (int hb = 0; hb < 2; ++hb)
    #pragma unroll
    for (int g = 0; g < 4; ++g) {
      uint2 u;
      u.x = cvtpk(oacc[hb][4 * g + 0], oacc[hb][4 * g + 1]);
      u.y = cvtpk(oacc[hb][4 * g + 2], oacc[hb][4 * g + 3]);
      *(uint2*)(Ob + ridx * 64 + hb * 32 + 8 * g + 4 * hi) = u;
    }
  if (hi == 0) ml[(size_t)part * 40 * Sc + ridx] = lrun;
}

// ---------------- Output projection, 64x64 tiles, combine fused into A-stage
// K-step kt covers columns [kt*64, kt*64+64) = head kt exactly, so the A tile
// at step kt is (Omb0+Omb1)/l for rows (b*20+kt)*2048+q. Reg-staged with the
// same swizzle invariant as gload16: LDS[row][c] = global chunk c^(row&7).
__global__ __launch_bounds__(256) void k_proj_o(
    const __bf16* __restrict__ Omb0, const __bf16* __restrict__ Omb1,
    const float* __restrict__ ml, const __bf16* __restrict__ WoT,
    const float* __restrict__ bo, float* __restrict__ Out)
{
  const int m0 = blockIdx.y * 64, n0 = blockIdx.x * 64;
  const int t = threadIdx.x, lane = t & 63, wv = t >> 6;
  const int l15 = lane & 15, l4 = lane >> 4;

  __shared__ __bf16 As[64 * 64];    // 8 KB
  __shared__ __bf16 Bs[64 * 64];    // 8 KB

  const int lrow = lane >> 3;
  const int lcol = ((lane & 7) ^ lrow) * 8;   // pre-swizzled source chunk
  const int ldst = (lane & 7) * 8;            // linear LDS dest chunk

  f32x4 acc[4];
  #pragma unroll
  for (int i = 0; i < 4; ++i)
    #pragma unroll
    for (int e = 0; e < 4; ++e) acc[i][e] = 0.0f;

  for (int kt = 0; kt < 20; ++kt) {
    const int k0 = kt * 64;
    #pragma unroll
    for (int s = 0; s < 2; ++s) {
      int row = wv * 16 + s * 8;
      // A: combine partials inline (head kt's rows)
      {
        int grow = m0 + row + lrow;               // global 0..4095
        int bb = grow >> 11, q = grow & (Sc - 1);
        size_t r = ((size_t)(bb * Hc + kt)) * Sc + q;
        bf16x8 o0 = *(const bf16x8*)(Omb0 + r * 64 + lcol);
        bf16x8 o1 = *(const bf16x8*)(Omb1 + r * 64 + lcol);
        float inv = 1.0f / (ml[r] + ml[(size_t)(40 * Sc) + r]);
        uint4 d;
        d.x = cvtpk(((float)o0[0] + (float)o1[0]) * inv, ((float)o0[1] + (float)o1[1]) * inv);
        d.y = cvtpk(((float)o0[2] + (float)o1[2]) * inv, ((float)o0[3] + (float)o1[3]) * inv);
        d.z = cvtpk(((float)o0[4] + (float)o1[4]) * inv, ((float)o0[5] + (float)o1[5]) * inv);
        d.w = cvtpk(((float)o0[6] + (float)o1[6]) * inv, ((float)o0[7] + (float)o1[7]) * inv);
        *(uint4*)(As + (row + lrow) * 64 + ldst) = d;
      }
      // B: direct global->LDS
      gload16(WoT + (size_t)(n0 + row + lrow) * Dc + k0 + lcol, Bs + row * 64);
    }
    __syncthreads();

    bf16x8 af[2][4], bfr[2];
    #pragma unroll
    for (int kc = 0; kc < 2; ++kc) {
      #pragma unroll
      for (int rs = 0; rs < 4; ++rs) {
        int rowa = rs * 16 + l15;
        int cha  = (kc * 4 + l4) ^ (rowa & 7);
        af[kc][rs] = *(const bf16x8*)(As + rowa * 64 + cha * 8);
      }
      int rowb = wv * 16 + l15;
      int chb  = (kc * 4 + l4) ^ (rowb & 7);
      bfr[kc] = *(const bf16x8*)(Bs + rowb * 64 + chb * 8);
    }
    #pragma unroll
    for (int kc = 0; kc < 2; ++kc)
      #pragma unroll
      for (int rs = 0; rs < 4; ++rs)
        acc[rs] = __builtin_amdgcn_mfma_f32_16x16x32_bf16(af[kc][rs], bfr[kc], acc[rs], 0, 0, 0);
    __syncthreads();
  }

  #pragma unroll
  for (int rs = 0; rs < 4; ++rs)
    #pragma unroll
    for (int r = 0; r < 4; ++r) {
      int row = m0 + rs * 16 + l4 * 4 + r;
      int col = n0 + wv * 16 + l15;
      Out[(size_t)row * Dc + col] = acc[rs][r] + bo[col];
    }
}

extern "C" void kernel_launch(void* const* d_in, const int* in_sizes, int n_in,
                              void* d_out, int out_size, void* d_ws, size_t ws_size,
                              hipStream_t stream) {
  const float* Xq  = (const float*)d_in[0];
  const float* Xkv = (const float*)d_in[1];
  const float* Wq = (const float*)d_in[3];
  const float* bq = (const float*)d_in[4];
  const float* Wk = (const float*)d_in[5];
  const float* bk = (const float*)d_in[6];
  const float* Wv = (const float*)d_in[7];
  const float* bv = (const float*)d_in[8];
  const float* Wo = (const float*)d_in[9];
  const float* bo = (const float*)d_in[10];
  float* Out = (float*)d_out;

  const size_t MD = (size_t)4096 * 1280;
  char* p = (char*)d_ws;
  __bf16* Qb   = (__bf16*)p; p += MD * 2;
  __bf16* Kb   = (__bf16*)p; p += MD * 2;
  __bf16* Xqb  = (__bf16*)p; p += MD * 2;   // dead after proj; reused as Omb0
  __bf16* Xkvb = (__bf16*)p; p += MD * 2;
  __bf16* Wt   = (__bf16*)p; p += (size_t)4 * Dc * Dc * 2;
  __bf16* Vtg  = (__bf16*)p; p += MD * 2;     // [b][h][hd][s]
  float* cosT  = (float*)p;  p += (size_t)Sc * 32 * 4;
  float* sinT  = (float*)p;  p += (size_t)Sc * 32 * 4;
  __bf16* Omb1 = (__bf16*)p; p += (size_t)40 * Sc * 64 * 2;   // 10.5MB
  float* mlbuf = (float*)p;  p += (size_t)2 * 40 * Sc * 4;
  __bf16* Omb0 = Xqb;   // aliases Xqb (dead by then; 10.5MB fits exactly)

  k_prep<<<12096, 256, 0, stream>>>(Xq, Xkv, Xqb, Xkvb, Wq, Wk, Wv, Wo, Wt,
                                    cosT, sinT);
  k_proj_qkv<<<dim3(10, 32, 3), 256, 0, stream>>>(Xqb, Xkvb, Wt, bq, bk, bv,
                                                  cosT, sinT, Qb, Kb, Vtg);
  k_attn<<<1280, 256, 0, stream>>>(Qb, Kb, Vtg, Omb0, Omb1, mlbuf);
  k_proj_o<<<dim3(20, 64), 256, 0, stream>>>(Omb0, Omb1, mlbuf,
                                             Wt + (size_t)3 * Dc * Dc, bo, Out);
}

// Round 19
// 177.624 us; speedup vs baseline: 1.0681x; 1.0681x over previous
//
#include <hip/hip_runtime.h>

// Problem: B=2, S=2048, D=1280, H=20, HD=64.  M = B*S = 4096.
#define Sc 2048
#define Dc 1280
#define Hc 20

typedef __bf16 bf16x8 __attribute__((ext_vector_type(8)));
typedef float f32x4 __attribute__((ext_vector_type(4)));
typedef float f32x16 __attribute__((ext_vector_type(16)));
typedef unsigned u32x2 __attribute__((ext_vector_type(2)));

__device__ __forceinline__ __bf16 tobf(float f) {
  union { float f; unsigned u; } a; a.f = f;
  unsigned r = (a.u + 0x7FFFu + ((a.u >> 16) & 1u)) >> 16;  // RNE
  union { unsigned short s; __bf16 b; } o; o.s = (unsigned short)r;
  return o.b;
}

__device__ __forceinline__ void gload16(const __bf16* g, __bf16* l) {
  __builtin_amdgcn_global_load_lds(
      (const __attribute__((address_space(1))) void*)(g),
      (__attribute__((address_space(3))) void*)(l), 16, 0, 0);
}

__device__ __forceinline__ unsigned cvtpk(float lo, float hi) {
  unsigned r;
  asm("v_cvt_pk_bf16_f32 %0, %1, %2" : "=v"(r) : "v"(lo), "v"(hi));
  return r;
}

__device__ __forceinline__ float fexp2(float x) {
#if __has_builtin(__builtin_amdgcn_exp2f)
  return __builtin_amdgcn_exp2f(x);
#else
  return exp2f(x);
#endif
}

__device__ __forceinline__ void plswap(unsigned &a, unsigned &b) {
#if __has_builtin(__builtin_amdgcn_permlane32_swap)
  u32x2 r = __builtin_amdgcn_permlane32_swap(a, b, false, false);
  a = r[0]; b = r[1];
#else
  asm volatile("v_permlane32_swap_b32 %0, %1" : "+v"(a), "+v"(b));
#endif
}

// ---------------- merged prep: cvtx (10240 blk) | wt (1600 blk) | rope (256) --
__global__ __launch_bounds__(256) void k_prep(
    const float* __restrict__ Xq, const float* __restrict__ Xkv,
    __bf16* __restrict__ Xqb, __bf16* __restrict__ Xkvb,
    const float* __restrict__ Wq, const float* __restrict__ Wk,
    const float* __restrict__ Wv, const float* __restrict__ Wo,
    __bf16* __restrict__ Wt,
    float* __restrict__ cosT, float* __restrict__ sinT)
{
  __shared__ __bf16 Ls[64][80];
  const int bid = blockIdx.x;
  const int t = threadIdx.x;
  if (bid < 10240) {
    // ---- X f32 -> bf16 ----
    const int half = bid >= 5120;
    const int i = (bid - (half ? 5120 : 0)) * 256 + t;
    const float* X = half ? Xkv : Xq;
    __bf16* O = half ? Xkvb : Xqb;
    float4 f = ((const float4*)X)[i];
    union { __bf16 b[4]; uint2 u; } pk;
    pk.b[0] = tobf(f.x); pk.b[1] = tobf(f.y); pk.b[2] = tobf(f.z); pk.b[3] = tobf(f.w);
    ((uint2*)O)[i] = pk.u;
  } else if (bid < 11840) {
    // ---- W [k][n] f32 -> Wt [z][n][k] bf16 ----
    int r = bid - 10240;
    const int z = r / 400; r %= 400;
    const int n0 = (r % 20) * 64, k0 = (r / 20) * 64;
    const float* W = (z == 0) ? Wq : (z == 1) ? Wk : (z == 2) ? Wv : Wo;
    __bf16* O = Wt + (size_t)z * Dc * Dc;
    #pragma unroll
    for (int i = 0; i < 4; ++i) {
      int c = t + 256 * i;
      int rr = c >> 4, cc = (c & 15) * 4;
      float4 f = *(const float4*)(W + (size_t)(k0 + rr) * Dc + n0 + cc);
      Ls[cc + 0][rr] = tobf(f.x);
      Ls[cc + 1][rr] = tobf(f.y);
      Ls[cc + 2][rr] = tobf(f.z);
      Ls[cc + 3][rr] = tobf(f.w);
    }
    __syncthreads();
    #pragma unroll
    for (int i = 0; i < 2; ++i) {
      int c = t + 256 * i;
      int rr = c >> 3, cc = (c & 7) * 8;
      *(bf16x8*)(O + (size_t)(n0 + rr) * Dc + k0 + cc) = *(const bf16x8*)(&Ls[rr][cc]);
    }
  } else {
    // ---- RoPE cos/sin table ----
    int i = (bid - 11840) * 256 + t;
    int s = i >> 5, f = i & 31;
    float inv = expf(-(float)f * (logf(10000.0f) / 32.0f));
    float th = (float)s * inv;
    cosT[i] = cosf(th);
    sinT[i] = sinf(th);
  }
}

// ---------------- QKV projection + bias + RoPE; V written pre-transposed ----
// 1-D grid 960, XCD-swizzled: XCD f&7 owns 12 (y,z) A-panel groups x 10
// n-tiles contiguously -> A panel fetched once per XCD, reused 10x from L2.
__global__ __launch_bounds__(256) void k_proj_qkv(
    const __bf16* __restrict__ Xqb, const __bf16* __restrict__ Xkvb,
    const __bf16* __restrict__ Wt,
    const float* __restrict__ Bq, const float* __restrict__ Bk, const float* __restrict__ Bv,
    const float* __restrict__ cosT, const float* __restrict__ sinT,
    __bf16* __restrict__ Qo, __bf16* __restrict__ Ko, __bf16* __restrict__ Vt)
{
  const int fb = blockIdx.x;           // 0..959
  const int xcd = fb & 7, ib = fb >> 3;  // ib 0..119
  const int g = xcd * 12 + ib / 10;      // 0..95 = (y,z) group
  const int z = g / 32, y = g % 32;
  const int m0 = y * 128, n0 = (ib % 10) * 128;

  const __bf16* A  = (z == 0) ? Xqb : Xkvb;
  const __bf16* Bm = Wt + (size_t)z * Dc * Dc;
  const float* Bi  = (z == 0) ? Bq : (z == 1) ? Bk : Bv;

  const int t = threadIdx.x, lane = t & 63, wv = t >> 6;
  const int wr = wv >> 1, wc = wv & 1;
  const int l15 = lane & 15, l4 = lane >> 4;

  __shared__ __bf16 SM[2 * 128 * 64];   // As | Bs ; reused as transpose buf
  __bf16* As = SM;
  __bf16* Bs = SM + 128 * 64;

  const int lrow = lane >> 3;
  const int lcol = ((lane & 7) ^ lrow) * 8;

  f32x4 acc[4][4];
  #pragma unroll
  for (int i = 0; i < 4; ++i)
    #pragma unroll
    for (int j = 0; j < 4; ++j)
      #pragma unroll
      for (int e = 0; e < 4; ++e) acc[i][j][e] = 0.0f;

  for (int kt = 0; kt < 20; ++kt) {
    const int k0 = kt * 64;
    #pragma unroll
    for (int s = 0; s < 4; ++s) {
      int row = wv * 32 + s * 8 + lrow;
      gload16(A  + (size_t)(m0 + row) * Dc + k0 + lcol, As + (wv * 32 + s * 8) * 64);
      gload16(Bm + (size_t)(n0 + row) * Dc + k0 + lcol, Bs + (wv * 32 + s * 8) * 64);
    }
    __syncthreads();

    bf16x8 af[2][4], bfr[2][4];
    #pragma unroll
    for (int kc = 0; kc < 2; ++kc)
      #pragma unroll
      for (int rs = 0; rs < 4; ++rs) {
        int rowa = wr * 64 + rs * 16 + l15;
        int cha  = (kc * 4 + l4) ^ (rowa & 7);
        af[kc][rs] = *(const bf16x8*)(As + rowa * 64 + cha * 8);
        int rowb = wc * 64 + rs * 16 + l15;
        int chb  = (kc * 4 + l4) ^ (rowb & 7);
        bfr[kc][rs] = *(const bf16x8*)(Bs + rowb * 64 + chb * 8);
      }
    #pragma unroll
    for (int kc = 0; kc < 2; ++kc)
      #pragma unroll
      for (int rs = 0; rs < 4; ++rs)
        #pragma unroll
        for (int cb = 0; cb < 4; ++cb)
          acc[rs][cb] = __builtin_amdgcn_mfma_f32_16x16x32_bf16(af[kc][rs], bfr[kc][cb], acc[rs][cb], 0, 0, 0);
    __syncthreads();
  }

  const int head = n0 / 64 + wc;
  if (z < 2) {
    __bf16* O = (z == 0) ? Qo : Ko;
    const float scale = (z == 0) ? 0.125f * 1.4426950408889634f : 1.0f;
    #pragma unroll
    for (int rs = 0; rs < 4; ++rs)
      #pragma unroll
      for (int r = 0; r < 4; ++r) {
        int row = m0 + wr * 64 + rs * 16 + l4 * 4 + r;
        int s = row & (Sc - 1);
        #pragma unroll
        for (int cb = 0; cb < 2; ++cb) {
          int hd = cb * 16 + l15;
          float c  = cosT[s * 32 + hd];
          float sn = sinT[s * 32 + hd];
          float xlo = acc[rs][cb][r]     + Bi[head * 64 + hd];
          float xhi = acc[rs][cb + 2][r] + Bi[head * 64 + hd + 32];
          O[(size_t)row * Dc + head * 64 + hd]      = tobf((xlo * c - xhi * sn) * scale);
          O[(size_t)row * Dc + head * 64 + hd + 32] = tobf((xhi * c + xlo * sn) * scale);
        }
      }
  } else {
    // V: transpose in LDS (swizzled), write Vt[b][h][hd][s] coalesced.
    #pragma unroll
    for (int rs = 0; rs < 4; ++rs)
      #pragma unroll
      for (int r = 0; r < 4; ++r) {
        int row128 = wr * 64 + rs * 16 + l4 * 4 + r;
        #pragma unroll
        for (int cb = 0; cb < 4; ++cb) {
          int hd = cb * 16 + l15;
          float v = acc[rs][cb][r] + Bi[n0 + wc * 64 + hd];
          SM[wc * 8192 + hd * 128 + (row128 ^ ((hd & 7) << 3))] = tobf(v);
        }
      }
    __syncthreads();
    const int bq_ = m0 >> 11, s0 = m0 & (Sc - 1);
    #pragma unroll
    for (int i = 0; i < 8; ++i) {
      int idx = t + 256 * i;        // 2048 chunks of 8
      int hd2 = idx >> 4, sc = idx & 15;
      int hh = hd2 >> 6, hd = hd2 & 63;
      int head2 = n0 / 64 + hh;
      bf16x8 vv = *(const bf16x8*)(&SM[hh * 8192 + hd * 128 + ((sc ^ (hd & 7)) << 3)]);
      *(bf16x8*)(Vt + ((size_t)((bq_ * Hc + head2) * 64 + hd)) * Sc + s0 + sc * 8) = vv;
    }
  }
}

// ---------------- Flash attention: T15 cross-tile pipeline (round-16 exact) -
__global__ __launch_bounds__(256) void k_attn(
    const __bf16* __restrict__ Qb, const __bf16* __restrict__ Kb,
    const __bf16* __restrict__ Vt,
    __bf16* __restrict__ Omb0, __bf16* __restrict__ Omb1, float* __restrict__ ml)
{
  const int f = blockIdx.x;            // 0..1279
  const int xcd = f & 7, ii = f >> 3;  // 0..159
  const int grp = xcd * 5 + (ii >> 5); // 0..39 = b*20+h
  const int rem = ii & 31;
  const int part = rem >> 4;           // 0..1
  const int qt   = rem & 15;           // 0..15
  const int h = grp % Hc, b = grp / Hc;
  const int kvbase = part * 1024;

  const int t = threadIdx.x, lane = t & 63, wv = t >> 6;   // wv 0..3
  const int l31 = lane & 31, hi = lane >> 5;

  __shared__ __bf16 Ks[3][64 * 64];
  __shared__ __bf16 Vs[3][64 * 64];

  const int q0 = qt * 128 + wv * 32;
  const size_t qrow = (size_t)(b * Sc + q0 + l31);

  bf16x8 qreg[4];
  #pragma unroll
  for (int kc = 0; kc < 4; ++kc)
    qreg[kc] = *(const bf16x8*)(Qb + qrow * Dc + h * 64 + kc * 16 + hi * 8);

  f32x16 zc;
  #pragma unroll
  for (int e = 0; e < 16; ++e) zc[e] = 0.0f;

  f32x16 oacc[2];
  oacc[0] = zc; oacc[1] = zc;
  float lrun = 0.0f;

  const int lrow = lane >> 3;
  const int lchunk = ((lane & 7) ^ lrow) * 8;
  const __bf16* Ksrc = Kb + (size_t)b * Sc * Dc + h * 64;
  const __bf16* Vsrc = Vt + (size_t)(b * Hc + h) * 64 * Sc;

  auto STAGE = [&](int t_) {
    int bb = t_ % 3;
    int kv0 = kvbase + t_ * 64;
    #pragma unroll
    for (int i = 0; i < 2; ++i) {
      int rowb = i * 32 + wv * 8;
      gload16(Ksrc + (size_t)(kv0 + rowb + lrow) * Dc + lchunk, &Ks[bb][rowb * 64]);
      gload16(Vsrc + (size_t)(rowb + lrow) * Sc + kv0 + lchunk, &Vs[bb][rowb * 64]);
    }
  };

  auto QK = [&](f32x16 (&s)[2], int t_) {
    const __bf16* Kbuf = &Ks[t_ % 3][0];
    __builtin_amdgcn_s_setprio(1);
    #pragma unroll
    for (int sub = 0; sub < 2; ++sub) {
      int row = sub * 32 + l31;
      {
        int ch = hi ^ (row & 7);
        bf16x8 kf = *(const bf16x8*)(Kbuf + row * 64 + ch * 8);
        s[sub] = __builtin_amdgcn_mfma_f32_32x32x16_bf16(kf, qreg[0], zc, 0, 0, 0);
      }
      #pragma unroll
      for (int kc = 1; kc < 4; ++kc) {
        int ch = (kc * 2 + hi) ^ (row & 7);
        bf16x8 kf = *(const bf16x8*)(Kbuf + row * 64 + ch * 8);
        s[sub] = __builtin_amdgcn_mfma_f32_32x32x16_bf16(kf, qreg[kc], s[sub], 0, 0, 0);
      }
    }
    __builtin_amdgcn_s_setprio(0);
  };

  // fused softmax + PV, per c16 group: exp2 x8 -> lsum -> pack -> 2 PV MFMAs
  auto SMPV = [&](const f32x16 (&s)[2], int t_) {
    const __bf16* Vbuf = &Vs[t_ % 3][0];
    const float* sp = (const float*)&s;
    #pragma unroll
    for (int c16 = 0; c16 < 4; ++c16) {
      float p0 = fexp2(sp[c16 * 8 + 0]), p1 = fexp2(sp[c16 * 8 + 1]);
      float p2 = fexp2(sp[c16 * 8 + 2]), p3 = fexp2(sp[c16 * 8 + 3]);
      float p4 = fexp2(sp[c16 * 8 + 4]), p5 = fexp2(sp[c16 * 8 + 5]);
      float p6 = fexp2(sp[c16 * 8 + 6]), p7 = fexp2(sp[c16 * 8 + 7]);
      lrun += ((p0 + p1) + (p2 + p3)) + ((p4 + p5) + (p6 + p7));
      unsigned w0 = cvtpk(p0, p1);
      unsigned w1 = cvtpk(p2, p3);
      unsigned w2 = cvtpk(p4, p5);
      unsigned w3 = cvtpk(p6, p7);
      plswap(w0, w2);
      plswap(w1, w3);
      union { unsigned w[4]; bf16x8 v; } pa;
      pa.w[0] = w0; pa.w[1] = w1; pa.w[2] = w2; pa.w[3] = w3;
      __builtin_amdgcn_s_setprio(1);
      #pragma unroll
      for (int hb = 0; hb < 2; ++hb) {
        int row = hb * 32 + l31;
        int ch = (c16 * 2 + hi) ^ (row & 7);
        bf16x8 vf = *(const bf16x8*)(Vbuf + row * 64 + ch * 8);
        oacc[hb] = __builtin_amdgcn_mfma_f32_32x32x16_bf16(vf, pa.v, oacc[hb], 0, 0, 0);
      }
      __builtin_amdgcn_s_setprio(0);
    }
  };

  f32x16 sA[2], sB[2];

  // prologue: tiles 0,1 staged and fully landed; QK(0)
  STAGE(0);
  STAGE(1);
  asm volatile("s_waitcnt vmcnt(0)\ns_barrier" ::: "memory");
  QK(sA, 0);

#define ATTN_ITER(T, SCUR, SNXT)                                          \
  {                                                                       \
    if ((T) <= 13) STAGE((T) + 2);                                        \
    if ((T) <= 14) QK(SNXT, (T) + 1);                                     \
    SMPV(SCUR, (T));                                                      \
    if ((T) <= 14) {                                                      \
      asm volatile("s_waitcnt vmcnt(0)\ns_barrier" ::: "memory");         \
    }                                                                     \
  }

  for (int tt = 0; tt < 8; ++tt) {
    ATTN_ITER(2 * tt, sA, sB);
    ATTN_ITER(2 * tt + 1, sB, sA);
  }
#undef ATTN_ITER

  // epilogue: cross-half l; bf16 unnormalized partial O^T -> Omb[part] + l
  lrun += __shfl_xor(lrun, 32);
  __bf16* Ob = part ? Omb1 : Omb0;
  const size_t ridx = (size_t)grp * Sc + q0 + l31;   // row within part
  #pragma unroll
  for (int hb = 0; hb < 2; ++hb)
    #pragma unroll
    for (int g = 0; g < 4; ++g) {
      uint2 u;
      u.x = cvtpk(oacc[hb][4 * g + 0], oacc[hb][4 * g + 1]);
      u.y = cvtpk(oacc[hb][4 * g + 2], oacc[hb][4 * g + 3]);
      *(uint2*)(Ob + ridx * 64 + hb * 32 + 8 * g + 4 * hi) = u;
    }
  if (hi == 0) ml[(size_t)part * 40 * Sc + ridx] = lrun;
}

// ---------------- combine the two KV-split bf16 partials -> Xb (bf16) ------
__global__ __launch_bounds__(256) void k_combine(
    const __bf16* __restrict__ Omb0, const __bf16* __restrict__ Omb1,
    const float* __restrict__ ml, __bf16* __restrict__ Xb)
{
  int idx = blockIdx.x * 256 + threadIdx.x;   // 81920 rows * 8 chunks = 655360
  int r = idx >> 3, c8 = (idx & 7) * 8;
  int grp = r >> 11, q = r & (Sc - 1);
  int b = grp / Hc, h = grp % Hc;
  float l0 = ml[(size_t)r];
  float l1 = ml[(size_t)(40 * Sc) + r];
  float inv = 1.0f / (l0 + l1);
  bf16x8 o0 = *(const bf16x8*)(Omb0 + (size_t)r * 64 + c8);
  bf16x8 o1 = *(const bf16x8*)(Omb1 + (size_t)r * 64 + c8);
  union { __bf16 b8[8]; bf16x8 v; } pk;
  #pragma unroll
  for (int j = 0; j < 8; ++j)
    pk.b8[j] = tobf(((float)o0[j] + (float)o1[j]) * inv);
  *(bf16x8*)(Xb + ((size_t)(b * Sc + q)) * Dc + h * 64 + c8) = pk.v;
}

// ---------------- Output projection, 64x64 tiles (grid 1280 = 5/CU) --------
__global__ __launch_bounds__(256) void k_proj_o(
    const __bf16* __restrict__ Xb, const __bf16* __restrict__ WoT,
    const float* __restrict__ bo, float* __restrict__ Out)
{
  const int m0 = blockIdx.y * 64, n0 = blockIdx.x * 64;
  const int t = threadIdx.x, lane = t & 63, wv = t >> 6;
  const int l15 = lane & 15, l4 = lane >> 4;

  __shared__ __bf16 As[64 * 64];    // 8 KB
  __shared__ __bf16 Bs[64 * 64];    // 8 KB

  const int lrow = lane >> 3;
  const int lcol = ((lane & 7) ^ lrow) * 8;

  f32x4 acc[4];
  #pragma unroll
  for (int i = 0; i < 4; ++i)
    #pragma unroll
    for (int e = 0; e < 4; ++e) acc[i][e] = 0.0f;

  for (int kt = 0; kt < 20; ++kt) {
    const int k0 = kt * 64;
    #pragma unroll
    for (int s = 0; s < 2; ++s) {
      int row = wv * 16 + s * 8;
      gload16(Xb  + (size_t)(m0 + row + lrow) * Dc + k0 + lcol, As + row * 64);
      gload16(WoT + (size_t)(n0 + row + lrow) * Dc + k0 + lcol, Bs + row * 64);
    }
    __syncthreads();

    bf16x8 af[2][4], bfr[2];
    #pragma unroll
    for (int kc = 0; kc < 2; ++kc) {
      #pragma unroll
      for (int rs = 0; rs < 4; ++rs) {
        int rowa = rs * 16 + l15;
        int cha  = (kc * 4 + l4) ^ (rowa & 7);
        af[kc][rs] = *(const bf16x8*)(As + rowa * 64 + cha * 8);
      }
      int rowb = wv * 16 + l15;
      int chb  = (kc * 4 + l4) ^ (rowb & 7);
      bfr[kc] = *(const bf16x8*)(Bs + rowb * 64 + chb * 8);
    }
    #pragma unroll
    for (int kc = 0; kc < 2; ++kc)
      #pragma unroll
      for (int rs = 0; rs < 4; ++rs)
        acc[rs] = __builtin_amdgcn_mfma_f32_16x16x32_bf16(af[kc][rs], bfr[kc], acc[rs], 0, 0, 0);
    __syncthreads();
  }

  #pragma unroll
  for (int rs = 0; rs < 4; ++rs)
    #pragma unroll
    for (int r = 0; r < 4; ++r) {
      int row = m0 + rs * 16 + l4 * 4 + r;
      int col = n0 + wv * 16 + l15;
      Out[(size_t)row * Dc + col] = acc[rs][r] + bo[col];
    }
}

extern "C" void kernel_launch(void* const* d_in, const int* in_sizes, int n_in,
                              void* d_out, int out_size, void* d_ws, size_t ws_size,
                              hipStream_t stream) {
  const float* Xq  = (const float*)d_in[0];
  const float* Xkv = (const float*)d_in[1];
  const float* Wq = (const float*)d_in[3];
  const float* bq = (const float*)d_in[4];
  const float* Wk = (const float*)d_in[5];
  const float* bk = (const float*)d_in[6];
  const float* Wv = (const float*)d_in[7];
  const float* bv = (const float*)d_in[8];
  const float* Wo = (const float*)d_in[9];
  const float* bo = (const float*)d_in[10];
  float* Out = (float*)d_out;

  const size_t MD = (size_t)4096 * 1280;
  char* p = (char*)d_ws;
  __bf16* Qb   = (__bf16*)p; p += MD * 2;
  __bf16* Kb   = (__bf16*)p; p += MD * 2;
  __bf16* Xb   = (__bf16*)p; p += MD * 2;
  __bf16* Xqb  = (__bf16*)p; p += MD * 2;   // dead after proj; reused as Omb0
  __bf16* Xkvb = (__bf16*)p; p += MD * 2;
  __bf16* Wt   = (__bf16*)p; p += (size_t)4 * Dc * Dc * 2;
  __bf16* Vtg  = (__bf16*)p; p += MD * 2;     // [b][h][hd][s]
  float* cosT  = (float*)p;  p += (size_t)Sc * 32 * 4;
  float* sinT  = (float*)p;  p += (size_t)Sc * 32 * 4;
  __bf16* Omb1 = (__bf16*)p; p += (size_t)40 * Sc * 64 * 2;   // 10.5MB
  float* mlbuf = (float*)p;  p += (size_t)2 * 40 * Sc * 4;
  __bf16* Omb0 = Xqb;   // aliases Xqb (dead by then; 10.5MB fits exactly)

  k_prep<<<12096, 256, 0, stream>>>(Xq, Xkv, Xqb, Xkvb, Wq, Wk, Wv, Wo, Wt,
                                    cosT, sinT);
  k_proj_qkv<<<960, 256, 0, stream>>>(Xqb, Xkvb, Wt, bq, bk, bv,
                                      cosT, sinT, Qb, Kb, Vtg);
  k_attn<<<1280, 256, 0, stream>>>(Qb, Kb, Vtg, Omb0, Omb1, mlbuf);
  k_combine<<<2560, 256, 0, stream>>>(Omb0, Omb1, mlbuf, Xb);
  k_proj_o<<<dim3(20, 64), 256, 0, stream>>>(Xb, Wt + (size_t)3 * Dc * Dc, bo, Out);
}

// Round 20
// 176.071 us; speedup vs baseline: 1.0775x; 1.0088x over previous
//
#include <hip/hip_runtime.h>

// Problem: B=2, S=2048, D=1280, H=20, HD=64.  M = B*S = 4096.
#define Sc 2048
#define Dc 1280
#define Hc 20

typedef __bf16 bf16x8 __attribute__((ext_vector_type(8)));
typedef float f32x4 __attribute__((ext_vector_type(4)));
typedef float f32x16 __attribute__((ext_vector_type(16)));
typedef unsigned u32x2 __attribute__((ext_vector_type(2)));

__device__ __forceinline__ __bf16 tobf(float f) {
  union { float f; unsigned u; } a; a.f = f;
  unsigned r = (a.u + 0x7FFFu + ((a.u >> 16) & 1u)) >> 16;  // RNE
  union { unsigned short s; __bf16 b; } o; o.s = (unsigned short)r;
  return o.b;
}

__device__ __forceinline__ void gload16(const __bf16* g, __bf16* l) {
  __builtin_amdgcn_global_load_lds(
      (const __attribute__((address_space(1))) void*)(g),
      (__attribute__((address_space(3))) void*)(l), 16, 0, 0);
}

__device__ __forceinline__ unsigned cvtpk(float lo, float hi) {
  unsigned r;
  asm("v_cvt_pk_bf16_f32 %0, %1, %2" : "=v"(r) : "v"(lo), "v"(hi));
  return r;
}

__device__ __forceinline__ float fexp2(float x) {
#if __has_builtin(__builtin_amdgcn_exp2f)
  return __builtin_amdgcn_exp2f(x);
#else
  return exp2f(x);
#endif
}

__device__ __forceinline__ void plswap(unsigned &a, unsigned &b) {
#if __has_builtin(__builtin_amdgcn_permlane32_swap)
  u32x2 r = __builtin_amdgcn_permlane32_swap(a, b, false, false);
  a = r[0]; b = r[1];
#else
  asm volatile("v_permlane32_swap_b32 %0, %1" : "+v"(a), "+v"(b));
#endif
}

// ---------------- merged prep: cvtx (10240 blk) | wt (1600 blk) | rope (256) --
__global__ __launch_bounds__(256) void k_prep(
    const float* __restrict__ Xq, const float* __restrict__ Xkv,
    __bf16* __restrict__ Xqb, __bf16* __restrict__ Xkvb,
    const float* __restrict__ Wq, const float* __restrict__ Wk,
    const float* __restrict__ Wv, const float* __restrict__ Wo,
    __bf16* __restrict__ Wt,
    float* __restrict__ cosT, float* __restrict__ sinT)
{
  __shared__ __bf16 Ls[64][80];
  const int bid = blockIdx.x;
  const int t = threadIdx.x;
  if (bid < 10240) {
    // ---- X f32 -> bf16 ----
    const int half = bid >= 5120;
    const int i = (bid - (half ? 5120 : 0)) * 256 + t;
    const float* X = half ? Xkv : Xq;
    __bf16* O = half ? Xkvb : Xqb;
    float4 f = ((const float4*)X)[i];
    union { __bf16 b[4]; uint2 u; } pk;
    pk.b[0] = tobf(f.x); pk.b[1] = tobf(f.y); pk.b[2] = tobf(f.z); pk.b[3] = tobf(f.w);
    ((uint2*)O)[i] = pk.u;
  } else if (bid < 11840) {
    // ---- W [k][n] f32 -> Wt [z][n][k] bf16 ----
    int r = bid - 10240;
    const int z = r / 400; r %= 400;
    const int n0 = (r % 20) * 64, k0 = (r / 20) * 64;
    const float* W = (z == 0) ? Wq : (z == 1) ? Wk : (z == 2) ? Wv : Wo;
    __bf16* O = Wt + (size_t)z * Dc * Dc;
    #pragma unroll
    for (int i = 0; i < 4; ++i) {
      int c = t + 256 * i;
      int rr = c >> 4, cc = (c & 15) * 4;
      float4 f = *(const float4*)(W + (size_t)(k0 + rr) * Dc + n0 + cc);
      Ls[cc + 0][rr] = tobf(f.x);
      Ls[cc + 1][rr] = tobf(f.y);
      Ls[cc + 2][rr] = tobf(f.z);
      Ls[cc + 3][rr] = tobf(f.w);
    }
    __syncthreads();
    #pragma unroll
    for (int i = 0; i < 2; ++i) {
      int c = t + 256 * i;
      int rr = c >> 3, cc = (c & 7) * 8;
      *(bf16x8*)(O + (size_t)(n0 + rr) * Dc + k0 + cc) = *(const bf16x8*)(&Ls[rr][cc]);
    }
  } else {
    // ---- RoPE cos/sin table ----
    int i = (bid - 11840) * 256 + t;
    int s = i >> 5, f = i & 31;
    float inv = expf(-(float)f * (logf(10000.0f) / 32.0f));
    float th = (float)s * inv;
    cosT[i] = cosf(th);
    sinT[i] = sinf(th);
  }
}

// ---------------- QKV projection + bias + RoPE; V written pre-transposed ----
// 1-D grid 960, XCD-swizzled: XCD f&7 owns 12 (y,z) A-panel groups x 10
// n-tiles contiguously -> A panel fetched once per XCD, reused 10x from L2.
__global__ __launch_bounds__(256) void k_proj_qkv(
    const __bf16* __restrict__ Xqb, const __bf16* __restrict__ Xkvb,
    const __bf16* __restrict__ Wt,
    const float* __restrict__ Bq, const float* __restrict__ Bk, const float* __restrict__ Bv,
    const float* __restrict__ cosT, const float* __restrict__ sinT,
    __bf16* __restrict__ Qo, __bf16* __restrict__ Ko, __bf16* __restrict__ Vt)
{
  const int fb = blockIdx.x;           // 0..959
  const int xcd = fb & 7, ib = fb >> 3;  // ib 0..119
  const int g = xcd * 12 + ib / 10;      // 0..95 = (y,z) group
  const int z = g / 32, y = g % 32;
  const int m0 = y * 128, n0 = (ib % 10) * 128;

  const __bf16* A  = (z == 0) ? Xqb : Xkvb;
  const __bf16* Bm = Wt + (size_t)z * Dc * Dc;
  const float* Bi  = (z == 0) ? Bq : (z == 1) ? Bk : Bv;

  const int t = threadIdx.x, lane = t & 63, wv = t >> 6;
  const int wr = wv >> 1, wc = wv & 1;
  const int l15 = lane & 15, l4 = lane >> 4;

  __shared__ __bf16 SM[2 * 128 * 64];   // As | Bs ; reused as transpose buf
  __bf16* As = SM;
  __bf16* Bs = SM + 128 * 64;

  const int lrow = lane >> 3;
  const int lcol = ((lane & 7) ^ lrow) * 8;

  f32x4 acc[4][4];
  #pragma unroll
  for (int i = 0; i < 4; ++i)
    #pragma unroll
    for (int j = 0; j < 4; ++j)
      #pragma unroll
      for (int e = 0; e < 4; ++e) acc[i][j][e] = 0.0f;

  for (int kt = 0; kt < 20; ++kt) {
    const int k0 = kt * 64;
    #pragma unroll
    for (int s = 0; s < 4; ++s) {
      int row = wv * 32 + s * 8 + lrow;
      gload16(A  + (size_t)(m0 + row) * Dc + k0 + lcol, As + (wv * 32 + s * 8) * 64);
      gload16(Bm + (size_t)(n0 + row) * Dc + k0 + lcol, Bs + (wv * 32 + s * 8) * 64);
    }
    __syncthreads();

    bf16x8 af[2][4], bfr[2][4];
    #pragma unroll
    for (int kc = 0; kc < 2; ++kc)
      #pragma unroll
      for (int rs = 0; rs < 4; ++rs) {
        int rowa = wr * 64 + rs * 16 + l15;
        int cha  = (kc * 4 + l4) ^ (rowa & 7);
        af[kc][rs] = *(const bf16x8*)(As + rowa * 64 + cha * 8);
        int rowb = wc * 64 + rs * 16 + l15;
        int chb  = (kc * 4 + l4) ^ (rowb & 7);
        bfr[kc][rs] = *(const bf16x8*)(Bs + rowb * 64 + chb * 8);
      }
    #pragma unroll
    for (int kc = 0; kc < 2; ++kc)
      #pragma unroll
      for (int rs = 0; rs < 4; ++rs)
        #pragma unroll
        for (int cb = 0; cb < 4; ++cb)
          acc[rs][cb] = __builtin_amdgcn_mfma_f32_16x16x32_bf16(af[kc][rs], bfr[kc][cb], acc[rs][cb], 0, 0, 0);
    __syncthreads();
  }

  const int head = n0 / 64 + wc;
  if (z < 2) {
    __bf16* O = (z == 0) ? Qo : Ko;
    const float scale = (z == 0) ? 0.125f * 1.4426950408889634f : 1.0f;
    #pragma unroll
    for (int rs = 0; rs < 4; ++rs)
      #pragma unroll
      for (int r = 0; r < 4; ++r) {
        int row = m0 + wr * 64 + rs * 16 + l4 * 4 + r;
        int s = row & (Sc - 1);
        #pragma unroll
        for (int cb = 0; cb < 2; ++cb) {
          int hd = cb * 16 + l15;
          float c  = cosT[s * 32 + hd];
          float sn = sinT[s * 32 + hd];
          float xlo = acc[rs][cb][r]     + Bi[head * 64 + hd];
          float xhi = acc[rs][cb + 2][r] + Bi[head * 64 + hd + 32];
          O[(size_t)row * Dc + head * 64 + hd]      = tobf((xlo * c - xhi * sn) * scale);
          O[(size_t)row * Dc + head * 64 + hd + 32] = tobf((xhi * c + xlo * sn) * scale);
        }
      }
  } else {
    // V: transpose in LDS (swizzled), write Vt[b][h][hd][s] coalesced.
    #pragma unroll
    for (int rs = 0; rs < 4; ++rs)
      #pragma unroll
      for (int r = 0; r < 4; ++r) {
        int row128 = wr * 64 + rs * 16 + l4 * 4 + r;
        #pragma unroll
        for (int cb = 0; cb < 4; ++cb) {
          int hd = cb * 16 + l15;
          float v = acc[rs][cb][r] + Bi[n0 + wc * 64 + hd];
          SM[wc * 8192 + hd * 128 + (row128 ^ ((hd & 7) << 3))] = tobf(v);
        }
      }
    __syncthreads();
    const int bq_ = m0 >> 11, s0 = m0 & (Sc - 1);
    #pragma unroll
    for (int i = 0; i < 8; ++i) {
      int idx = t + 256 * i;        // 2048 chunks of 8
      int hd2 = idx >> 4, sc = idx & 15;
      int hh = hd2 >> 6, hd = hd2 & 63;
      int head2 = n0 / 64 + hh;
      bf16x8 vv = *(const bf16x8*)(&SM[hh * 8192 + hd * 128 + ((sc ^ (hd & 7)) << 3)]);
      *(bf16x8*)(Vt + ((size_t)((bq_ * Hc + head2) * 64 + hd)) * Sc + s0 + sc * 8) = vv;
    }
  }
}

// ---------------- Flash attention: T15 cross-tile pipeline (round-16 exact) -
__global__ __launch_bounds__(256) void k_attn(
    const __bf16* __restrict__ Qb, const __bf16* __restrict__ Kb,
    const __bf16* __restrict__ Vt,
    __bf16* __restrict__ Omb0, __bf16* __restrict__ Omb1, float* __restrict__ ml)
{
  const int f = blockIdx.x;            // 0..1279
  const int xcd = f & 7, ii = f >> 3;  // 0..159
  const int grp = xcd * 5 + (ii >> 5); // 0..39 = b*20+h
  const int rem = ii & 31;
  const int part = rem >> 4;           // 0..1
  const int qt   = rem & 15;           // 0..15
  const int h = grp % Hc, b = grp / Hc;
  const int kvbase = part * 1024;

  const int t = threadIdx.x, lane = t & 63, wv = t >> 6;   // wv 0..3
  const int l31 = lane & 31, hi = lane >> 5;

  __shared__ __bf16 Ks[3][64 * 64];
  __shared__ __bf16 Vs[3][64 * 64];

  const int q0 = qt * 128 + wv * 32;
  const size_t qrow = (size_t)(b * Sc + q0 + l31);

  bf16x8 qreg[4];
  #pragma unroll
  for (int kc = 0; kc < 4; ++kc)
    qreg[kc] = *(const bf16x8*)(Qb + qrow * Dc + h * 64 + kc * 16 + hi * 8);

  f32x16 zc;
  #pragma unroll
  for (int e = 0; e < 16; ++e) zc[e] = 0.0f;

  f32x16 oacc[2];
  oacc[0] = zc; oacc[1] = zc;
  float lrun = 0.0f;

  const int lrow = lane >> 3;
  const int lchunk = ((lane & 7) ^ lrow) * 8;
  const __bf16* Ksrc = Kb + (size_t)b * Sc * Dc + h * 64;
  const __bf16* Vsrc = Vt + (size_t)(b * Hc + h) * 64 * Sc;

  auto STAGE = [&](int t_) {
    int bb = t_ % 3;
    int kv0 = kvbase + t_ * 64;
    #pragma unroll
    for (int i = 0; i < 2; ++i) {
      int rowb = i * 32 + wv * 8;
      gload16(Ksrc + (size_t)(kv0 + rowb + lrow) * Dc + lchunk, &Ks[bb][rowb * 64]);
      gload16(Vsrc + (size_t)(rowb + lrow) * Sc + kv0 + lchunk, &Vs[bb][rowb * 64]);
    }
  };

  auto QK = [&](f32x16 (&s)[2], int t_) {
    const __bf16* Kbuf = &Ks[t_ % 3][0];
    __builtin_amdgcn_s_setprio(1);
    #pragma unroll
    for (int sub = 0; sub < 2; ++sub) {
      int row = sub * 32 + l31;
      {
        int ch = hi ^ (row & 7);
        bf16x8 kf = *(const bf16x8*)(Kbuf + row * 64 + ch * 8);
        s[sub] = __builtin_amdgcn_mfma_f32_32x32x16_bf16(kf, qreg[0], zc, 0, 0, 0);
      }
      #pragma unroll
      for (int kc = 1; kc < 4; ++kc) {
        int ch = (kc * 2 + hi) ^ (row & 7);
        bf16x8 kf = *(const bf16x8*)(Kbuf + row * 64 + ch * 8);
        s[sub] = __builtin_amdgcn_mfma_f32_32x32x16_bf16(kf, qreg[kc], s[sub], 0, 0, 0);
      }
    }
    __builtin_amdgcn_s_setprio(0);
  };

  // fused softmax + PV, per c16 group: exp2 x8 -> lsum -> pack -> 2 PV MFMAs
  auto SMPV = [&](const f32x16 (&s)[2], int t_) {
    const __bf16* Vbuf = &Vs[t_ % 3][0];
    const float* sp = (const float*)&s;
    #pragma unroll
    for (int c16 = 0; c16 < 4; ++c16) {
      float p0 = fexp2(sp[c16 * 8 + 0]), p1 = fexp2(sp[c16 * 8 + 1]);
      float p2 = fexp2(sp[c16 * 8 + 2]), p3 = fexp2(sp[c16 * 8 + 3]);
      float p4 = fexp2(sp[c16 * 8 + 4]), p5 = fexp2(sp[c16 * 8 + 5]);
      float p6 = fexp2(sp[c16 * 8 + 6]), p7 = fexp2(sp[c16 * 8 + 7]);
      lrun += ((p0 + p1) + (p2 + p3)) + ((p4 + p5) + (p6 + p7));
      unsigned w0 = cvtpk(p0, p1);
      unsigned w1 = cvtpk(p2, p3);
      unsigned w2 = cvtpk(p4, p5);
      unsigned w3 = cvtpk(p6, p7);
      plswap(w0, w2);
      plswap(w1, w3);
      union { unsigned w[4]; bf16x8 v; } pa;
      pa.w[0] = w0; pa.w[1] = w1; pa.w[2] = w2; pa.w[3] = w3;
      __builtin_amdgcn_s_setprio(1);
      #pragma unroll
      for (int hb = 0; hb < 2; ++hb) {
        int row = hb * 32 + l31;
        int ch = (c16 * 2 + hi) ^ (row & 7);
        bf16x8 vf = *(const bf16x8*)(Vbuf + row * 64 + ch * 8);
        oacc[hb] = __builtin_amdgcn_mfma_f32_32x32x16_bf16(vf, pa.v, oacc[hb], 0, 0, 0);
      }
      __builtin_amdgcn_s_setprio(0);
    }
  };

  f32x16 sA[2], sB[2];

  // prologue: tiles 0,1 staged and fully landed; QK(0)
  STAGE(0);
  STAGE(1);
  asm volatile("s_waitcnt vmcnt(0)\ns_barrier" ::: "memory");
  QK(sA, 0);

#define ATTN_ITER(T, SCUR, SNXT)                                          \
  {                                                                       \
    if ((T) <= 13) STAGE((T) + 2);                                        \
    if ((T) <= 14) QK(SNXT, (T) + 1);                                     \
    SMPV(SCUR, (T));                                                      \
    if ((T) <= 14) {                                                      \
      asm volatile("s_waitcnt vmcnt(0)\ns_barrier" ::: "memory");         \
    }                                                                     \
  }

  for (int tt = 0; tt < 8; ++tt) {
    ATTN_ITER(2 * tt, sA, sB);
    ATTN_ITER(2 * tt + 1, sB, sA);
  }
#undef ATTN_ITER

  // epilogue: cross-half l; bf16 unnormalized partial O^T -> Omb[part] + l
  lrun += __shfl_xor(lrun, 32);
  __bf16* Ob = part ? Omb1 : Omb0;
  const size_t ridx = (size_t)grp * Sc + q0 + l31;   // row within part
  #pragma unroll
  for (int hb = 0; hb < 2; ++hb)
    #pragma unroll
    for (int g = 0; g < 4; ++g) {
      uint2 u;
      u.x = cvtpk(oacc[hb][4 * g + 0], oacc[hb][4 * g + 1]);
      u.y = cvtpk(oacc[hb][4 * g + 2], oacc[hb][4 * g + 3]);
      *(uint2*)(Ob + ridx * 64 + hb * 32 + 8 * g + 4 * hi) = u;
    }
  if (hi == 0) ml[(size_t)part * 40 * Sc + ridx] = lrun;
}

// ---------------- combine the two KV-split bf16 partials -> Xb (bf16) ------
__global__ __launch_bounds__(256) void k_combine(
    const __bf16* __restrict__ Omb0, const __bf16* __restrict__ Omb1,
    const float* __restrict__ ml, __bf16* __restrict__ Xb)
{
  int idx = blockIdx.x * 256 + threadIdx.x;   // 81920 rows * 8 chunks = 655360
  int r = idx >> 3, c8 = (idx & 7) * 8;
  int grp = r >> 11, q = r & (Sc - 1);
  int b = grp / Hc, h = grp % Hc;
  float l0 = ml[(size_t)r];
  float l1 = ml[(size_t)(40 * Sc) + r];
  float inv = 1.0f / (l0 + l1);
  bf16x8 o0 = *(const bf16x8*)(Omb0 + (size_t)r * 64 + c8);
  bf16x8 o1 = *(const bf16x8*)(Omb1 + (size_t)r * 64 + c8);
  union { __bf16 b8[8]; bf16x8 v; } pk;
  #pragma unroll
  for (int j = 0; j < 8; ++j)
    pk.b8[j] = tobf(((float)o0[j] + (float)o1[j]) * inv);
  *(bf16x8*)(Xb + ((size_t)(b * Sc + q)) * Dc + h * 64 + c8) = pk.v;
}

// ---------------- Output projection, 64x64 tiles, XCD-swizzled 1-D grid -----
// 1280 = 8 x 160: XCD f&7 owns 8 whole m-panel groups x 20 n-tiles
// contiguously -> each A panel fetched by exactly one XCD's L2.
__global__ __launch_bounds__(256) void k_proj_o(
    const __bf16* __restrict__ Xb, const __bf16* __restrict__ WoT,
    const float* __restrict__ bo, float* __restrict__ Out)
{
  const int fb = blockIdx.x;            // 0..1279
  const int xcd = fb & 7, ib = fb >> 3; // ib 0..159
  const int y = xcd * 8 + ib / 20;      // 0..63 m-group
  const int m0 = y * 64, n0 = (ib % 20) * 64;

  const int t = threadIdx.x, lane = t & 63, wv = t >> 6;
  const int l15 = lane & 15, l4 = lane >> 4;

  __shared__ __bf16 As[64 * 64];    // 8 KB
  __shared__ __bf16 Bs[64 * 64];    // 8 KB

  const int lrow = lane >> 3;
  const int lcol = ((lane & 7) ^ lrow) * 8;

  f32x4 acc[4];
  #pragma unroll
  for (int i = 0; i < 4; ++i)
    #pragma unroll
    for (int e = 0; e < 4; ++e) acc[i][e] = 0.0f;

  for (int kt = 0; kt < 20; ++kt) {
    const int k0 = kt * 64;
    #pragma unroll
    for (int s = 0; s < 2; ++s) {
      int row = wv * 16 + s * 8;
      gload16(Xb  + (size_t)(m0 + row + lrow) * Dc + k0 + lcol, As + row * 64);
      gload16(WoT + (size_t)(n0 + row + lrow) * Dc + k0 + lcol, Bs + row * 64);
    }
    __syncthreads();

    bf16x8 af[2][4], bfr[2];
    #pragma unroll
    for (int kc = 0; kc < 2; ++kc) {
      #pragma unroll
      for (int rs = 0; rs < 4; ++rs) {
        int rowa = rs * 16 + l15;
        int cha  = (kc * 4 + l4) ^ (rowa & 7);
        af[kc][rs] = *(const bf16x8*)(As + rowa * 64 + cha * 8);
      }
      int rowb = wv * 16 + l15;
      int chb  = (kc * 4 + l4) ^ (rowb & 7);
      bfr[kc] = *(const bf16x8*)(Bs + rowb * 64 + chb * 8);
    }
    #pragma unroll
    for (int kc = 0; kc < 2; ++kc)
      #pragma unroll
      for (int rs = 0; rs < 4; ++rs)
        acc[rs] = __builtin_amdgcn_mfma_f32_16x16x32_bf16(af[kc][rs], bfr[kc], acc[rs], 0, 0, 0);
    __syncthreads();
  }

  #pragma unroll
  for (int rs = 0; rs < 4; ++rs)
    #pragma unroll
    for (int r = 0; r < 4; ++r) {
      int row = m0 + rs * 16 + l4 * 4 + r;
      int col = n0 + wv * 16 + l15;
      Out[(size_t)row * Dc + col] = acc[rs][r] + bo[col];
    }
}

extern "C" void kernel_launch(void* const* d_in, const int* in_sizes, int n_in,
                              void* d_out, int out_size, void* d_ws, size_t ws_size,
                              hipStream_t stream) {
  const float* Xq  = (const float*)d_in[0];
  const float* Xkv = (const float*)d_in[1];
  const float* Wq = (const float*)d_in[3];
  const float* bq = (const float*)d_in[4];
  const float* Wk = (const float*)d_in[5];
  const float* bk = (const float*)d_in[6];
  const float* Wv = (const float*)d_in[7];
  const float* bv = (const float*)d_in[8];
  const float* Wo = (const float*)d_in[9];
  const float* bo = (const float*)d_in[10];
  float* Out = (float*)d_out;

  const size_t MD = (size_t)4096 * 1280;
  char* p = (char*)d_ws;
  __bf16* Qb   = (__bf16*)p; p += MD * 2;
  __bf16* Kb   = (__bf16*)p; p += MD * 2;
  __bf16* Xb   = (__bf16*)p; p += MD * 2;
  __bf16* Xqb  = (__bf16*)p; p += MD * 2;   // dead after proj; reused as Omb0
  __bf16* Xkvb = (__bf16*)p; p += MD * 2;
  __bf16* Wt   = (__bf16*)p; p += (size_t)4 * Dc * Dc * 2;
  __bf16* Vtg  = (__bf16*)p; p += MD * 2;     // [b][h][hd][s]
  float* cosT  = (float*)p;  p += (size_t)Sc * 32 * 4;
  float* sinT  = (float*)p;  p += (size_t)Sc * 32 * 4;
  __bf16* Omb1 = (__bf16*)p; p += (size_t)40 * Sc * 64 * 2;   // 10.5MB
  float* mlbuf = (float*)p;  p += (size_t)2 * 40 * Sc * 4;
  __bf16* Omb0 = Xqb;   // aliases Xqb (dead by then; 10.5MB fits exactly)

  k_prep<<<12096, 256, 0, stream>>>(Xq, Xkv, Xqb, Xkvb, Wq, Wk, Wv, Wo, Wt,
                                    cosT, sinT);
  k_proj_qkv<<<960, 256, 0, stream>>>(Xqb, Xkvb, Wt, bq, bk, bv,
                                      cosT, sinT, Qb, Kb, Vtg);
  k_attn<<<1280, 256, 0, stream>>>(Qb, Kb, Vtg, Omb0, Omb1, mlbuf);
  k_combine<<<2560, 256, 0, stream>>>(Omb0, Omb1, mlbuf, Xb);
  k_proj_o<<<1280, 256, 0, stream>>>(Xb, Wt + (size_t)3 * Dc * Dc, bo, Out);
}